// Round 1
// baseline (4955.938 us; speedup 1.0000x reference)
//
#include <hip/hip_runtime.h>
#include <math.h>

// Problem constants (from reference)
#define BDIM 2
#define TDIM 2048
#define CDIM 1024
#define HDIM 16
#define DDIM 64

// ---------------------------------------------------------------------------
// GEMM: out[M,N] = A[M,K] @ W[K,N] + bias[N]   (all fp32, row-major)
// 64x64 tile, BK=16, 256 threads, 4x4 microtile per thread.
// ---------------------------------------------------------------------------
template <int BM, int BN, int BK>
__global__ __launch_bounds__(256) void gemm_bias(
    const float* __restrict__ A, const float* __restrict__ W,
    const float* __restrict__ bias, float* __restrict__ out,
    int M, int N, int K) {
  __shared__ float As[BK][BM + 1];  // +1 pad: transpose-store would be 16-way conflicted
  __shared__ float Bs[BK][BN];

  const int tid = threadIdx.x;
  const int rowBase = blockIdx.y * BM;
  const int colBase = blockIdx.x * BN;
  const int tr = tid / 16;  // 0..15
  const int tc = tid % 16;  // 0..15

  // global-load assignments (each thread: one float4 of A, one float4 of W)
  const int a_row = tid / 4;         // 0..63
  const int a_col = (tid % 4) * 4;   // 0,4,8,12
  const int b_row = tid / 16;        // 0..15
  const int b_col = (tid % 16) * 4;  // 0..60

  float acc[4][4] = {};

  for (int k0 = 0; k0 < K; k0 += BK) {
    float4 av = *(const float4*)&A[(size_t)(rowBase + a_row) * K + k0 + a_col];
    float4 bv = *(const float4*)&W[(size_t)(k0 + b_row) * N + colBase + b_col];
    As[a_col + 0][a_row] = av.x;
    As[a_col + 1][a_row] = av.y;
    As[a_col + 2][a_row] = av.z;
    As[a_col + 3][a_row] = av.w;
    *(float4*)&Bs[b_row][b_col] = bv;
    __syncthreads();

#pragma unroll
    for (int kk = 0; kk < BK; ++kk) {
      float a[4], b[4];
#pragma unroll
      for (int i = 0; i < 4; ++i) a[i] = As[kk][tr * 4 + i];
#pragma unroll
      for (int j = 0; j < 4; ++j) b[j] = Bs[kk][tc * 4 + j];
#pragma unroll
      for (int i = 0; i < 4; ++i)
#pragma unroll
        for (int j = 0; j < 4; ++j) acc[i][j] = fmaf(a[i], b[j], acc[i][j]);
    }
    __syncthreads();
  }

#pragma unroll
  for (int i = 0; i < 4; ++i) {
    const int r = rowBase + tr * 4 + i;
#pragma unroll
    for (int j = 0; j < 4; ++j) {
      const int cIdx = colBase + tc * 4 + j;
      out[(size_t)r * N + cIdx] = acc[i][j] + bias[cIdx];
    }
  }
}

// ---------------------------------------------------------------------------
// Flash-style causal attention, fp32.
// q,k,v,ctx layout: [B, T, H, D] (i.e. the natural [B,T,C] reshape).
// Block: 256 threads = 32 q-rows x 8 "dim groups" of 8 dims each.
// Grid: (T/32, B*H). K/V tiles of 32 rows staged in LDS.
// ---------------------------------------------------------------------------
#define TQ 32
#define TKT 32

__global__ __launch_bounds__(256) void attention_fwd(
    const float* __restrict__ q, const float* __restrict__ k,
    const float* __restrict__ v, float* __restrict__ ctx) {
  __shared__ float q_lds[TQ][DDIM];
  __shared__ float k_lds[TKT][DDIM];
  __shared__ float v_lds[TKT][DDIM];
  __shared__ float s_lds[TQ][TKT + 1];

  const int tid = threadIdx.x;
  const int qtile = blockIdx.x;
  const int bh = blockIdx.y;
  const int b = bh / HDIM;
  const int h = bh % HDIM;
  const int qbase = qtile * TQ;
  const float scale = 0.125f;  // D^-0.5, D=64

  // load Q tile (2048 floats, 8 per thread, coalesced)
  {
    const int e = tid * 8;
    const int row = e / DDIM, col = e % DDIM;
    const float* src =
        &q[((size_t)(b * TDIM + qbase + row)) * CDIM + h * DDIM + col];
    float4 v0 = *(const float4*)&src[0];
    float4 v1 = *(const float4*)&src[4];
    *(float4*)&q_lds[row][col] = v0;
    *(float4*)&q_lds[row][col + 4] = v1;
  }

  const int r = tid / 8;   // q row within tile
  const int c = tid % 8;   // dim group
  const int d0 = c * 8;
  const int qi = qbase + r;

  float o[8] = {};
  float m = -1e30f, l = 0.f;

  const int nkt = qtile + 1;  // causal: only tiles with kbase <= qbase+TQ-1
  for (int kt = 0; kt < nkt; ++kt) {
    const int kbase = kt * TKT;
    __syncthreads();  // previous iter's consumers done (also covers q_lds write)
    {
      const int e = tid * 8;
      const int row = e / DDIM, col = e % DDIM;
      const size_t off =
          ((size_t)(b * TDIM + kbase + row)) * CDIM + h * DDIM + col;
      float4 k0 = *(const float4*)&k[off];
      float4 k1 = *(const float4*)&k[off + 4];
      float4 w0 = *(const float4*)&v[off];
      float4 w1 = *(const float4*)&v[off + 4];
      *(float4*)&k_lds[row][col] = k0;
      *(float4*)&k_lds[row][col + 4] = k1;
      *(float4*)&v_lds[row][col] = w0;
      *(float4*)&v_lds[row][col + 4] = w1;
    }
    __syncthreads();

    // scores: thread computes s[r][c*4 .. c*4+3]
#pragma unroll
    for (int jj = 0; jj < 4; ++jj) {
      const int j = c * 4 + jj;
      float dot = 0.f;
#pragma unroll
      for (int d4 = 0; d4 < DDIM; d4 += 4) {
        float4 qa = *(const float4*)&q_lds[r][d4];
        float4 kb = *(const float4*)&k_lds[j][d4];
        dot = fmaf(qa.x, kb.x, dot);
        dot = fmaf(qa.y, kb.y, dot);
        dot = fmaf(qa.z, kb.z, dot);
        dot = fmaf(qa.w, kb.w, dot);
      }
      const int kj = kbase + j;
      s_lds[r][j] = dot * scale + (kj <= qi ? 0.f : -1e9f);
    }
    __syncthreads();

    // online softmax update for row r (redundant across the 8 dim-group
    // threads of the same row — all compute identical m,l)
    float mt = -1e30f;
#pragma unroll
    for (int j = 0; j < TKT; ++j) mt = fmaxf(mt, s_lds[r][j]);
    const float m_new = fmaxf(m, mt);
    const float corr = expf(m - m_new);
    l *= corr;
#pragma unroll
    for (int dd = 0; dd < 8; ++dd) o[dd] *= corr;
#pragma unroll
    for (int j = 0; j < TKT; ++j) {
      const float p = expf(s_lds[r][j] - m_new);
      l += p;
      float4 va = *(const float4*)&v_lds[j][d0];
      float4 vb = *(const float4*)&v_lds[j][d0 + 4];
      o[0] = fmaf(p, va.x, o[0]);
      o[1] = fmaf(p, va.y, o[1]);
      o[2] = fmaf(p, va.z, o[2]);
      o[3] = fmaf(p, va.w, o[3]);
      o[4] = fmaf(p, vb.x, o[4]);
      o[5] = fmaf(p, vb.y, o[5]);
      o[6] = fmaf(p, vb.z, o[6]);
      o[7] = fmaf(p, vb.w, o[7]);
    }
    m = m_new;
  }

  const float invl = 1.f / l;
  const size_t outOff = ((size_t)(b * TDIM + qi)) * CDIM + h * DDIM + d0;
  float4 o0 = {o[0] * invl, o[1] * invl, o[2] * invl, o[3] * invl};
  float4 o1 = {o[4] * invl, o[5] * invl, o[6] * invl, o[7] * invl};
  *(float4*)&ctx[outOff] = o0;
  *(float4*)&ctx[outOff + 4] = o1;
}

// ---------------------------------------------------------------------------
extern "C" void kernel_launch(void* const* d_in, const int* in_sizes, int n_in,
                              void* d_out, int out_size, void* d_ws,
                              size_t ws_size, hipStream_t stream) {
  // setup_inputs order:
  // 0 hidden_states, 1 attention_mask, 2 Wq, 3 bq, 4 Wk, 5 bk, 6 Wv, 7 bv,
  // 8 Wo, 9 bo, 10 Wr1, 11 br1, 12 Wr2, 13 br2  (10..13 dead code)
  const float* hs = (const float*)d_in[0];
  const float* Wq = (const float*)d_in[2];
  const float* bq = (const float*)d_in[3];
  const float* Wk = (const float*)d_in[4];
  const float* bk = (const float*)d_in[5];
  const float* Wv = (const float*)d_in[6];
  const float* bv = (const float*)d_in[7];
  const float* Wo = (const float*)d_in[8];
  const float* bo = (const float*)d_in[9];
  float* out = (float*)d_out;

  const size_t NTOK = (size_t)BDIM * TDIM;  // 4096
  float* q = (float*)d_ws;
  float* k = q + NTOK * CDIM;
  float* v = k + NTOK * CDIM;
  float* ctx = v + NTOK * CDIM;
  // ws needed: 4 * 4096*1024 * 4B = 64 MB

  dim3 blk(256);
  dim3 ggrid(CDIM / 64, NTOK / 64);  // (16, 64)

  gemm_bias<64, 64, 16><<<ggrid, blk, 0, stream>>>(hs, Wq, bq, q, (int)NTOK,
                                                   CDIM, CDIM);
  gemm_bias<64, 64, 16><<<ggrid, blk, 0, stream>>>(hs, Wk, bk, k, (int)NTOK,
                                                   CDIM, CDIM);
  gemm_bias<64, 64, 16><<<ggrid, blk, 0, stream>>>(hs, Wv, bv, v, (int)NTOK,
                                                   CDIM, CDIM);

  dim3 agrid(TDIM / TQ, BDIM * HDIM);  // (64, 32)
  attention_fwd<<<agrid, blk, 0, stream>>>(q, k, v, ctx);

  gemm_bias<64, 64, 16><<<ggrid, blk, 0, stream>>>(ctx, Wo, bo, out, (int)NTOK,
                                                   CDIM, CDIM);
}

// Round 3
// 1859.388 us; speedup vs baseline: 2.6654x; 2.6654x over previous
//
#include <hip/hip_runtime.h>
#include <math.h>

// Problem constants (from reference)
#define BDIM 2
#define TDIM 2048
#define CDIM 1024
#define HDIM 16
#define DDIM 64
#define KT 16  // k-rows per staged tile

// ---------------------------------------------------------------------------
// GEMM: out[M,N] = A[M,K] @ W[K,N] + bias[N]   (all fp32, row-major)
// 64x64 tile, BK=16, 256 threads, 4x4 microtile per thread. (~95us, 90 TF)
// ---------------------------------------------------------------------------
template <int BM, int BN, int BK>
__global__ __launch_bounds__(256) void gemm_bias(
    const float* __restrict__ A, const float* __restrict__ W,
    const float* __restrict__ bias, float* __restrict__ out,
    int M, int N, int K) {
  __shared__ float As[BK][BM + 1];
  __shared__ float Bs[BK][BN];

  const int tid = threadIdx.x;
  const int rowBase = blockIdx.y * BM;
  const int colBase = blockIdx.x * BN;
  const int tr = tid / 16;
  const int tc = tid % 16;

  const int a_row = tid / 4;
  const int a_col = (tid % 4) * 4;
  const int b_row = tid / 16;
  const int b_col = (tid % 16) * 4;

  float acc[4][4] = {};

  for (int k0 = 0; k0 < K; k0 += BK) {
    float4 av = *(const float4*)&A[(size_t)(rowBase + a_row) * K + k0 + a_col];
    float4 bv = *(const float4*)&W[(size_t)(k0 + b_row) * N + colBase + b_col];
    As[a_col + 0][a_row] = av.x;
    As[a_col + 1][a_row] = av.y;
    As[a_col + 2][a_row] = av.z;
    As[a_col + 3][a_row] = av.w;
    *(float4*)&Bs[b_row][b_col] = bv;
    __syncthreads();

#pragma unroll
    for (int kk = 0; kk < BK; ++kk) {
      float a[4], b[4];
#pragma unroll
      for (int i = 0; i < 4; ++i) a[i] = As[kk][tr * 4 + i];
#pragma unroll
      for (int j = 0; j < 4; ++j) b[j] = Bs[kk][tc * 4 + j];
#pragma unroll
      for (int i = 0; i < 4; ++i)
#pragma unroll
        for (int j = 0; j < 4; ++j) acc[i][j] = fmaf(a[i], b[j], acc[i][j]);
    }
    __syncthreads();
  }

#pragma unroll
  for (int i = 0; i < 4; ++i) {
    const int r = rowBase + tr * 4 + i;
#pragma unroll
    for (int j = 0; j < 4; ++j) {
      const int cIdx = colBase + tc * 4 + j;
      out[(size_t)r * N + cIdx] = acc[i][j] + bias[cIdx];
    }
  }
}

// ---------------------------------------------------------------------------
// Flash attention, fp32, broadcast-LDS design.
// One WAVE (64 threads) per block; each lane owns one q row (q & o in regs).
// K/V tiles (16 rows) double-buffered in LDS via global_load_lds (width 16),
// pipelined with counted vmcnt. All compute-phase LDS reads are wave-uniform
// (broadcast) -> zero bank conflicts. No __syncthreads (single wave).
// Grid: (T/64 reversed for causal balance, B*H).
// ---------------------------------------------------------------------------
#define GLL16(gsrc, ldst)                                                      \
  __builtin_amdgcn_global_load_lds(                                            \
      (const __attribute__((address_space(1))) unsigned int*)(gsrc),           \
      (__attribute__((address_space(3))) unsigned int*)(ldst), 16, 0, 0)

__device__ __forceinline__ void stage_tile(const float* ksrc, const float* vsrc,
                                           float (*kl)[DDIM],
                                           float (*vl)[DDIM]) {
  // Each call: 64 lanes x 16B = 1024B = 4 rows of 64 f32. 4 calls per matrix.
  // LDS dest is linear (wave-uniform base + lane*16) matching [16][64] layout.
#pragma unroll
  for (int c = 0; c < 4; ++c) {
    GLL16(ksrc + (size_t)c * 4 * CDIM, &kl[c * 4][0]);
    GLL16(vsrc + (size_t)c * 4 * CDIM, &vl[c * 4][0]);
  }
}

__global__ __launch_bounds__(64) void attention_fwd(
    const float* __restrict__ q, const float* __restrict__ k,
    const float* __restrict__ v, float* __restrict__ ctx) {
  __shared__ float k_lds[2][KT][DDIM];
  __shared__ float v_lds[2][KT][DDIM];

  const int lane = threadIdx.x;
  const int qt = gridDim.x - 1 - blockIdx.x;  // big tiles first (balance)
  const int bh = blockIdx.y;
  const int b = bh >> 4;
  const int h = bh & 15;
  const int qbase = qt * 64;
  const int qi = qbase + lane;

  // q row -> registers (16 float4)
  float4 qreg[16];
  {
    const float* qrow = q + ((size_t)(b * TDIM + qi)) * CDIM + h * DDIM;
#pragma unroll
    for (int i = 0; i < 16; ++i) qreg[i] = ((const float4*)qrow)[i];
  }

  // per-lane staging source base: lane l covers row l/16, cols (l%16)*4..+3
  const int lrow = lane >> 4;
  const int lcol = (lane & 15) * 4;
  const float* kbasep =
      k + ((size_t)b * TDIM + lrow) * CDIM + h * DDIM + lcol;
  const float* vbasep =
      v + ((size_t)b * TDIM + lrow) * CDIM + h * DDIM + lcol;

  float o[DDIM] = {};
  float m = -3.0e38f, l = 0.0f;

  const int nkt = qt * 4 + 4;  // 16-row tiles covering rows 0..qbase+63

  stage_tile(kbasep, vbasep, k_lds[0], v_lds[0]);

  for (int kt = 0; kt < nkt; ++kt) {
    const int cur = kt & 1;
    if (kt + 1 < nkt) {
      stage_tile(kbasep + (size_t)(kt + 1) * KT * CDIM,
                 vbasep + (size_t)(kt + 1) * KT * CDIM, k_lds[cur ^ 1],
                 v_lds[cur ^ 1]);
      // current tile's 8 loads are the oldest; next tile's 8 stay in flight
      asm volatile("s_waitcnt vmcnt(8)" ::: "memory");
    } else {
      asm volatile("s_waitcnt vmcnt(0)" ::: "memory");
    }
    __builtin_amdgcn_sched_barrier(0);

    const int kbase = kt * KT;

    // ---- scores: 16 dots, all k_lds reads wave-uniform (broadcast) ----
    float s[KT];
#pragma unroll
    for (int jj = 0; jj < KT; ++jj) {
      float d0 = 0.f, d1 = 0.f, d2 = 0.f, d3 = 0.f;
#pragma unroll
      for (int d4 = 0; d4 < 16; ++d4) {
        float4 kv = *(const float4*)&k_lds[cur][jj][d4 * 4];
        float4 qv = qreg[d4];
        d0 = fmaf(qv.x, kv.x, d0);
        d1 = fmaf(qv.y, kv.y, d1);
        d2 = fmaf(qv.z, kv.z, d2);
        d3 = fmaf(qv.w, kv.w, d3);
      }
      const float dot = (d0 + d1) + (d2 + d3);
      s[jj] = (kbase + jj <= qi) ? dot * 0.125f : -3.0e38f;
    }

    // ---- online softmax (per-lane, register-resident) ----
    float pmax = s[0];
#pragma unroll
    for (int jj = 1; jj < KT; ++jj) pmax = fmaxf(pmax, s[jj]);
    const float m_new = fmaxf(m, pmax);
    const float corr = __expf(m - m_new);
    l *= corr;
#pragma unroll
    for (int d = 0; d < DDIM; ++d) o[d] *= corr;
    float p[KT];
#pragma unroll
    for (int jj = 0; jj < KT; ++jj) {
      p[jj] = __expf(s[jj] - m_new);
      l += p[jj];
    }
    m = m_new;

    // ---- PV: v_lds reads wave-uniform (broadcast) ----
#pragma unroll
    for (int jj = 0; jj < KT; ++jj) {
#pragma unroll
      for (int d4 = 0; d4 < 16; ++d4) {
        float4 vv = *(const float4*)&v_lds[cur][jj][d4 * 4];
        o[d4 * 4 + 0] = fmaf(p[jj], vv.x, o[d4 * 4 + 0]);
        o[d4 * 4 + 1] = fmaf(p[jj], vv.y, o[d4 * 4 + 1]);
        o[d4 * 4 + 2] = fmaf(p[jj], vv.z, o[d4 * 4 + 2]);
        o[d4 * 4 + 3] = fmaf(p[jj], vv.w, o[d4 * 4 + 3]);
      }
    }
  }

  // ---- epilogue ----
  const float invl = 1.0f / l;
  float* orow = ctx + ((size_t)(b * TDIM + qi)) * CDIM + h * DDIM;
#pragma unroll
  for (int d4 = 0; d4 < 16; ++d4) {
    float4 ov;
    ov.x = o[d4 * 4 + 0] * invl;
    ov.y = o[d4 * 4 + 1] * invl;
    ov.z = o[d4 * 4 + 2] * invl;
    ov.w = o[d4 * 4 + 3] * invl;
    ((float4*)orow)[d4] = ov;
  }
}

// ---------------------------------------------------------------------------
extern "C" void kernel_launch(void* const* d_in, const int* in_sizes, int n_in,
                              void* d_out, int out_size, void* d_ws,
                              size_t ws_size, hipStream_t stream) {
  // 0 hidden_states, 1 attention_mask(unused: implicit causal), 2 Wq, 3 bq,
  // 4 Wk, 5 bk, 6 Wv, 7 bv, 8 Wo, 9 bo, 10..13 routing MLP (dead code)
  const float* hs = (const float*)d_in[0];
  const float* Wq = (const float*)d_in[2];
  const float* bq = (const float*)d_in[3];
  const float* Wk = (const float*)d_in[4];
  const float* bk = (const float*)d_in[5];
  const float* Wv = (const float*)d_in[6];
  const float* bv = (const float*)d_in[7];
  const float* Wo = (const float*)d_in[8];
  const float* bo = (const float*)d_in[9];
  float* out = (float*)d_out;

  const size_t NTOK = (size_t)BDIM * TDIM;  // 4096
  float* q = (float*)d_ws;
  float* k = q + NTOK * CDIM;
  float* v = k + NTOK * CDIM;
  float* ctx = v + NTOK * CDIM;  // total 64 MB of d_ws

  dim3 blk(256);
  dim3 ggrid(CDIM / 64, NTOK / 64);  // (16, 64)

  gemm_bias<64, 64, 16><<<ggrid, blk, 0, stream>>>(hs, Wq, bq, q, (int)NTOK,
                                                   CDIM, CDIM);
  gemm_bias<64, 64, 16><<<ggrid, blk, 0, stream>>>(hs, Wk, bk, k, (int)NTOK,
                                                   CDIM, CDIM);
  gemm_bias<64, 64, 16><<<ggrid, blk, 0, stream>>>(hs, Wv, bv, v, (int)NTOK,
                                                   CDIM, CDIM);

  dim3 ablk(64);
  dim3 agrid(TDIM / 64, BDIM * HDIM);  // (32, 32), 1 wave per block
  attention_fwd<<<agrid, ablk, 0, stream>>>(q, k, v, ctx);

  gemm_bias<64, 64, 16><<<ggrid, blk, 0, stream>>>(ctx, Wo, bo, out, (int)NTOK,
                                                   CDIM, CDIM);
}

// Round 4
// 996.147 us; speedup vs baseline: 4.9751x; 1.8666x over previous
//
#include <hip/hip_runtime.h>
#include <hip/hip_fp16.h>
#include <math.h>

// Problem constants
#define BDIM 2
#define TDIM 2048
#define CDIM 1024
#define HDIM 16
#define DDIM 64
#define AKT 8  // attention k-rows per staged tile

typedef _Float16 f16x8 __attribute__((ext_vector_type(8)));
typedef float f32x4 __attribute__((ext_vector_type(4)));

#define GLL16(gsrc, ldst)                                                      \
  __builtin_amdgcn_global_load_lds(                                            \
      (const __attribute__((address_space(1))) unsigned int*)(gsrc),           \
      (__attribute__((address_space(3))) unsigned int*)(ldst), 16, 0, 0)

// ---------------------------------------------------------------------------
// fp32 -> fp16 elementwise convert (8 elems/thread)
// ---------------------------------------------------------------------------
__global__ __launch_bounds__(256) void cvt_f16(const float* __restrict__ in,
                                               __half* __restrict__ out,
                                               int n8) {
  int i = blockIdx.x * blockDim.x + threadIdx.x;
  if (i >= n8) return;
  const float4* p = (const float4*)in + (size_t)i * 2;
  float4 a = p[0], b = p[1];
  __half2* o = (__half2*)out + (size_t)i * 4;
  o[0] = __floats2half2_rn(a.x, a.y);
  o[1] = __floats2half2_rn(a.z, a.w);
  o[2] = __floats2half2_rn(b.x, b.y);
  o[3] = __floats2half2_rn(b.z, b.w);
}

// ---------------------------------------------------------------------------
// W [K=1024][N=1024] f32  ->  Wt [N][K] f16   (z selects which of 4 matrices)
// ---------------------------------------------------------------------------
__global__ __launch_bounds__(256) void transpose_cvt(
    const float* __restrict__ w0, const float* __restrict__ w1,
    const float* __restrict__ w2, const float* __restrict__ w3,
    __half* __restrict__ o0, __half* __restrict__ o1,
    __half* __restrict__ o2, __half* __restrict__ o3) {
  const float* src;
  __half* dst;
  switch (blockIdx.z) {
    case 0: src = w0; dst = o0; break;
    case 1: src = w1; dst = o1; break;
    case 2: src = w2; dst = o2; break;
    default: src = w3; dst = o3; break;
  }
  __shared__ float t[32][33];
  const int tx = threadIdx.x & 31, ty = threadIdx.x >> 5;  // 32 x 8
  const int k0 = blockIdx.y * 32, n0 = blockIdx.x * 32;
#pragma unroll
  for (int j = 0; j < 4; ++j)
    t[ty + j * 8][tx] = src[(size_t)(k0 + ty + j * 8) * CDIM + n0 + tx];
  __syncthreads();
#pragma unroll
  for (int j = 0; j < 4; ++j)
    dst[(size_t)(n0 + ty + j * 8) * CDIM + k0 + tx] =
        __float2half(t[tx][ty + j * 8]);
}

// ---------------------------------------------------------------------------
// MFMA GEMM: out[M][N] f32 = A16[M][K] @ Bt16[N][K]^T + bias
// 128x128 tile, BK=32, 4 waves (2x2 of 64x64), mfma_f32_16x16x32_f16.
// A/B frag: row(col)=lane&15, k=(lane>>4)*8+r (contiguous 16B ds_read_b128).
// C/D frag: col=lane&15, row=(lane>>4)*4+j (verified layout).
// ---------------------------------------------------------------------------
__global__ __launch_bounds__(256) void gemm_f16_bt(
    const __half* __restrict__ A, const __half* __restrict__ Bt,
    const float* __restrict__ bias, float* __restrict__ out, int M, int N,
    int K) {
  __shared__ _Float16 As[128][32];
  __shared__ _Float16 Bs[128][32];
  const int tid = threadIdx.x;
  const int wid = tid >> 6, lane = tid & 63;
  const int m0 = blockIdx.y * 128, n0 = blockIdx.x * 128;
  const int wr = (wid >> 1) * 64, wc = (wid & 1) * 64;
  const int srow = lane >> 2;       // 0..15 (staging row within 16)
  const int scol = (lane & 3) * 8;  // f16 col chunk

  f32x4 acc[4][4] = {};

  for (int k0 = 0; k0 < K; k0 += 32) {
    // stage A,B tiles: per wave 2+2 global_load_lds (1KB each, linear dest)
    GLL16(A + (size_t)(m0 + wid * 32 + srow) * K + k0 + scol,
          &As[wid * 32][0]);
    GLL16(A + (size_t)(m0 + wid * 32 + 16 + srow) * K + k0 + scol,
          &As[wid * 32 + 16][0]);
    GLL16(Bt + (size_t)(n0 + wid * 32 + srow) * K + k0 + scol,
          &Bs[wid * 32][0]);
    GLL16(Bt + (size_t)(n0 + wid * 32 + 16 + srow) * K + k0 + scol,
          &Bs[wid * 32 + 16][0]);
    asm volatile("s_waitcnt vmcnt(0)" ::: "memory");
    __syncthreads();

    f16x8 a[4], b[4];
#pragma unroll
    for (int m = 0; m < 4; ++m)
      a[m] = *(const f16x8*)&As[wr + m * 16 + (lane & 15)][(lane >> 4) * 8];
#pragma unroll
    for (int n = 0; n < 4; ++n)
      b[n] = *(const f16x8*)&Bs[wc + n * 16 + (lane & 15)][(lane >> 4) * 8];
#pragma unroll
    for (int m = 0; m < 4; ++m)
#pragma unroll
      for (int n = 0; n < 4; ++n)
        acc[m][n] =
            __builtin_amdgcn_mfma_f32_16x16x32_f16(a[m], b[n], acc[m][n], 0, 0, 0);
    __syncthreads();
  }

#pragma unroll
  for (int m = 0; m < 4; ++m)
#pragma unroll
    for (int n = 0; n < 4; ++n) {
      const int col = n0 + wc + n * 16 + (lane & 15);
      const float bb = bias[col];
#pragma unroll
      for (int j = 0; j < 4; ++j) {
        const int row = m0 + wr + m * 16 + (lane >> 4) * 4 + j;
        out[(size_t)row * N + col] = acc[m][n][j] + bb;
      }
    }
}

// ---------------------------------------------------------------------------
// Flash attention fp32, in-block split-K x4.
// Block = 256 threads = 4 waves; all waves own the SAME 64 q rows
// (lane = row, q & o in registers); wave w processes k-chunk w
// (2*(qt+1) tiles of 8 rows). Merge (m,l,o) via LDS at the end.
// All compute-phase LDS reads are wave-uniform broadcasts (0 conflicts).
// Output written directly as fp16 for the Wo MFMA GEMM.
// ---------------------------------------------------------------------------
__device__ __forceinline__ void stage_kv(const float* ksrc, const float* vsrc,
                                         float* kl, float* vl) {
  GLL16(ksrc, kl);
  GLL16(vsrc, vl);
  GLL16(ksrc + 4 * CDIM, kl + 4 * DDIM);
  GLL16(vsrc + 4 * CDIM, vl + 4 * DDIM);
}

__global__ __launch_bounds__(256) void attention_fwd(
    const float* __restrict__ q, const float* __restrict__ k,
    const float* __restrict__ v, __half* __restrict__ ctx) {
  __shared__ float k_lds[4][2][AKT][DDIM];  // 16 KB
  __shared__ float v_lds[4][2][AKT][DDIM];  // 16 KB
  __shared__ float comb_m[4][64], comb_l[4][64];
  __shared__ float inv_l[64];
  __shared__ float o_acc[64][65];  // +1 pad

  const int tid = threadIdx.x;
  const int wid = tid >> 6, lane = tid & 63;
  const int qt = gridDim.x - 1 - blockIdx.x;  // big tiles first
  const int bh = blockIdx.y;
  const int b = bh >> 4, h = bh & 15;
  const int qbase = qt * 64;
  const int qi = qbase + lane;

  // q row -> registers
  float4 qreg[16];
  {
    const float* qrow = q + ((size_t)(b * TDIM + qi)) * CDIM + h * DDIM;
#pragma unroll
    for (int i = 0; i < 16; ++i) qreg[i] = ((const float4*)qrow)[i];
  }

  const int lrow = lane >> 4, lcol = (lane & 15) * 4;
  const float* kb = k + ((size_t)b * TDIM + lrow) * CDIM + h * DDIM + lcol;
  const float* vb = v + ((size_t)b * TDIM + lrow) * CDIM + h * DDIM + lcol;

  float o[DDIM] = {};
  float m = -3.0e38f, l = 0.0f;

  const int nt = (qt + 1) * 2;   // tiles in this wave's chunk
  const int t0 = wid * nt;       // first tile index

  stage_kv(kb + (size_t)(t0 * AKT) * CDIM, vb + (size_t)(t0 * AKT) * CDIM,
           &k_lds[wid][0][0][0], &v_lds[wid][0][0][0]);

  for (int ti = 0; ti < nt; ++ti) {
    const int cur = ti & 1;
    if (ti + 1 < nt) {
      const size_t off = (size_t)((t0 + ti + 1) * AKT) * CDIM;
      stage_kv(kb + off, vb + off, &k_lds[wid][cur ^ 1][0][0],
               &v_lds[wid][cur ^ 1][0][0]);
      asm volatile("s_waitcnt vmcnt(4)" ::: "memory");
    } else {
      asm volatile("s_waitcnt vmcnt(0)" ::: "memory");
    }
    __builtin_amdgcn_sched_barrier(0);

    const int kbase = (t0 + ti) * AKT;

    // scores (broadcast k_lds reads)
    float s[AKT];
#pragma unroll
    for (int jj = 0; jj < AKT; ++jj) {
      float d0 = 0.f, d1 = 0.f, d2 = 0.f, d3 = 0.f;
#pragma unroll
      for (int d4 = 0; d4 < 16; ++d4) {
        float4 kv = *(const float4*)&k_lds[wid][cur][jj][d4 * 4];
        float4 qv = qreg[d4];
        d0 = fmaf(qv.x, kv.x, d0);
        d1 = fmaf(qv.y, kv.y, d1);
        d2 = fmaf(qv.z, kv.z, d2);
        d3 = fmaf(qv.w, kv.w, d3);
      }
      const float dot = (d0 + d1) + (d2 + d3);
      s[jj] = (kbase + jj <= qi) ? dot * 0.125f : -3.0e38f;
    }

    // online softmax (m_use guard handles fully-masked tiles: p underflows 0)
    float pmax = s[0];
#pragma unroll
    for (int jj = 1; jj < AKT; ++jj) pmax = fmaxf(pmax, s[jj]);
    const float m_new = fmaxf(m, pmax);
    const float m_use = fmaxf(m_new, -1.0e30f);
    const float corr = __expf(m - m_new);  // 0 if m=-3e38,m_new real; 1 if both
    l *= corr;
#pragma unroll
    for (int d = 0; d < DDIM; ++d) o[d] *= corr;
    float p[AKT];
#pragma unroll
    for (int jj = 0; jj < AKT; ++jj) {
      p[jj] = __expf(s[jj] - m_use);
      l += p[jj];
    }
    m = m_new;

    // PV (broadcast v_lds reads)
#pragma unroll
    for (int jj = 0; jj < AKT; ++jj) {
#pragma unroll
      for (int d4 = 0; d4 < 16; ++d4) {
        float4 vv = *(const float4*)&v_lds[wid][cur][jj][d4 * 4];
        o[d4 * 4 + 0] = fmaf(p[jj], vv.x, o[d4 * 4 + 0]);
        o[d4 * 4 + 1] = fmaf(p[jj], vv.y, o[d4 * 4 + 1]);
        o[d4 * 4 + 2] = fmaf(p[jj], vv.z, o[d4 * 4 + 2]);
        o[d4 * 4 + 3] = fmaf(p[jj], vv.w, o[d4 * 4 + 3]);
      }
    }
  }

  // ---- cross-wave combine ----
  comb_m[wid][lane] = m;
  comb_l[wid][lane] = l;
  __syncthreads();
  const float mstar =
      fmaxf(fmaxf(comb_m[0][lane], comb_m[1][lane]),
            fmaxf(comb_m[2][lane], comb_m[3][lane]));  // > -1e30 (chunk 0 valid)
  const float alpha = __expf(m - mstar);
  float lstar = 0.f;
#pragma unroll
  for (int w = 0; w < 4; ++w)
    lstar += __expf(comb_m[w][lane] - mstar) * comb_l[w][lane];
  if (wid == 0) inv_l[lane] = 1.0f / lstar;

  for (int w = 0; w < 4; ++w) {
    if (wid == w) {
      if (w == 0) {
#pragma unroll
        for (int d = 0; d < DDIM; ++d) o_acc[lane][d] = alpha * o[d];
      } else {
#pragma unroll
        for (int d = 0; d < DDIM; ++d) o_acc[lane][d] += alpha * o[d];
      }
    }
    __syncthreads();
  }

  // ---- write ctx as fp16, coalesced ----
#pragma unroll
  for (int i = 0; i < 4; ++i) {
    const int idx = tid + i * 256;  // 0..1023 = 64 rows x 16 float4-chunks
    const int row = idx >> 4, c = (idx & 15) * 4;
    const float il = inv_l[row];
    __half2 h0 = __floats2half2_rn(o_acc[row][c] * il, o_acc[row][c + 1] * il);
    __half2 h1 =
        __floats2half2_rn(o_acc[row][c + 2] * il, o_acc[row][c + 3] * il);
    __half2* dst = (__half2*)(ctx + ((size_t)(b * TDIM + qbase + row)) * CDIM +
                              h * DDIM + c);
    dst[0] = h0;
    dst[1] = h1;
  }
}

// ---------------------------------------------------------------------------
extern "C" void kernel_launch(void* const* d_in, const int* in_sizes, int n_in,
                              void* d_out, int out_size, void* d_ws,
                              size_t ws_size, hipStream_t stream) {
  // 0 hs, 1 mask(unused), 2 Wq, 3 bq, 4 Wk, 5 bk, 6 Wv, 7 bv, 8 Wo, 9 bo,
  // 10..13 routing MLP (dead code)
  const float* hs = (const float*)d_in[0];
  const float* Wq = (const float*)d_in[2];
  const float* bq = (const float*)d_in[3];
  const float* Wk = (const float*)d_in[4];
  const float* bk = (const float*)d_in[5];
  const float* Wv = (const float*)d_in[6];
  const float* bv = (const float*)d_in[7];
  const float* Wo = (const float*)d_in[8];
  const float* bo = (const float*)d_in[9];
  float* out = (float*)d_out;

  const size_t NTOK = (size_t)BDIM * TDIM;  // 4096
  const size_t NELEM = NTOK * CDIM;         // 4M

  // d_ws layout (exactly 64 MB):
  //  q,k,v f32 (48MB) | hs16/ctx16 alias f16 (8MB) | WqT,WkT,WvT,WoT f16 (8MB)
  float* q = (float*)d_ws;
  float* k = q + NELEM;
  float* v = k + NELEM;
  __half* hs16 = (__half*)(v + NELEM);
  __half* ctx16 = hs16;  // alias: hs16 dead after QKV GEMMs
  __half* wqt = hs16 + NELEM;
  __half* wkt = wqt + (size_t)CDIM * CDIM;
  __half* wvt = wkt + (size_t)CDIM * CDIM;
  __half* wot = wvt + (size_t)CDIM * CDIM;

  // 1) convert hs -> fp16
  cvt_f16<<<dim3((NELEM / 8 + 255) / 256), dim3(256), 0, stream>>>(
      hs, hs16, (int)(NELEM / 8));

  // 2) transpose+convert the 4 weight matrices
  transpose_cvt<<<dim3(32, 32, 4), dim3(256), 0, stream>>>(
      Wq, Wk, Wv, Wo, wqt, wkt, wvt, wot);

  // 3) QKV projections (MFMA fp16)
  dim3 gblk(256), ggrid(CDIM / 128, NTOK / 128);  // (8, 32)
  gemm_f16_bt<<<ggrid, gblk, 0, stream>>>(hs16, wqt, bq, q, (int)NTOK, CDIM,
                                          CDIM);
  gemm_f16_bt<<<ggrid, gblk, 0, stream>>>(hs16, wkt, bk, k, (int)NTOK, CDIM,
                                          CDIM);
  gemm_f16_bt<<<ggrid, gblk, 0, stream>>>(hs16, wvt, bv, v, (int)NTOK, CDIM,
                                          CDIM);

  // 4) attention (fp32 math, fp16 output) — writes ctx16 (aliases hs16, dead)
  attention_fwd<<<dim3(TDIM / 64, BDIM * HDIM), dim3(256), 0, stream>>>(
      q, k, v, ctx16);

  // 5) output projection (MFMA fp16)
  gemm_f16_bt<<<ggrid, gblk, 0, stream>>>(ctx16, wot, bo, out, (int)NTOK, CDIM,
                                          CDIM);
}

// Round 5
// 366.595 us; speedup vs baseline: 13.5188x; 2.7173x over previous
//
#include <hip/hip_runtime.h>
#include <hip/hip_fp16.h>
#include <math.h>

// Problem constants
#define BDIM 2
#define TDIM 2048
#define CDIM 1024
#define HDIM 16
#define DDIM 64

typedef _Float16 f16x8 __attribute__((ext_vector_type(8)));
typedef float f32x4 __attribute__((ext_vector_type(4)));

#define GLL16(gsrc, ldst)                                                      \
  __builtin_amdgcn_global_load_lds(                                            \
      (const __attribute__((address_space(1))) unsigned int*)(gsrc),           \
      (__attribute__((address_space(3))) unsigned int*)(ldst), 16, 0, 0)

// XOR swizzle for 128B-stride LDS tiles: spreads 16B slots across banks.
#define SWZ(row) ((((row)&7) ^ (((row) >> 3) & 7)) << 4)

// ---------------------------------------------------------------------------
// fp32 -> fp16 elementwise convert (8 elems/thread)
// ---------------------------------------------------------------------------
__global__ __launch_bounds__(256) void cvt_f16(const float* __restrict__ in,
                                               __half* __restrict__ out,
                                               int n8) {
  int i = blockIdx.x * blockDim.x + threadIdx.x;
  if (i >= n8) return;
  const float4* p = (const float4*)in + (size_t)i * 2;
  float4 a = p[0], b = p[1];
  __half2* o = (__half2*)out + (size_t)i * 4;
  o[0] = __floats2half2_rn(a.x, a.y);
  o[1] = __floats2half2_rn(a.z, a.w);
  o[2] = __floats2half2_rn(b.x, b.y);
  o[3] = __floats2half2_rn(b.z, b.w);
}

// ---------------------------------------------------------------------------
// W [K][N] f32  ->  Wt [N][K] f16   (z selects which of 4 matrices)
// ---------------------------------------------------------------------------
__global__ __launch_bounds__(256) void transpose_cvt(
    const float* __restrict__ w0, const float* __restrict__ w1,
    const float* __restrict__ w2, const float* __restrict__ w3,
    __half* __restrict__ o0, __half* __restrict__ o1, __half* __restrict__ o2,
    __half* __restrict__ o3) {
  const float* src;
  __half* dst;
  switch (blockIdx.z) {
    case 0: src = w0; dst = o0; break;
    case 1: src = w1; dst = o1; break;
    case 2: src = w2; dst = o2; break;
    default: src = w3; dst = o3; break;
  }
  __shared__ float t[32][33];
  const int tx = threadIdx.x & 31, ty = threadIdx.x >> 5;  // 32 x 8
  const int k0 = blockIdx.y * 32, n0 = blockIdx.x * 32;
#pragma unroll
  for (int j = 0; j < 4; ++j)
    t[ty + j * 8][tx] = src[(size_t)(k0 + ty + j * 8) * CDIM + n0 + tx];
  __syncthreads();
#pragma unroll
  for (int j = 0; j < 4; ++j)
    dst[(size_t)(n0 + ty + j * 8) * CDIM + k0 + tx] =
        __float2half(t[tx][ty + j * 8]);
}

// ---------------------------------------------------------------------------
// MFMA GEMM: out[M][N] = A16[M][K] @ Bt16[N][K]^T + bias; out f32 or f16.
// 128x128 tile, BK=32, 4 waves (2x2 of 64x64), mfma_f32_16x16x32_f16.
// ---------------------------------------------------------------------------
template <int OUT16>
__global__ __launch_bounds__(256) void gemm_f16_bt(
    const __half* __restrict__ A, const __half* __restrict__ Bt,
    const float* __restrict__ bias, float* __restrict__ outf,
    __half* __restrict__ outh, int M, int N, int K) {
  __shared__ _Float16 As[128][32];
  __shared__ _Float16 Bs[128][32];
  const int tid = threadIdx.x;
  const int wid = tid >> 6, lane = tid & 63;
  const int m0 = blockIdx.y * 128, n0 = blockIdx.x * 128;
  const int wr = (wid >> 1) * 64, wc = (wid & 1) * 64;
  const int srow = lane >> 2;
  const int scol = (lane & 3) * 8;

  f32x4 acc[4][4] = {};

  for (int k0 = 0; k0 < K; k0 += 32) {
    GLL16(A + (size_t)(m0 + wid * 32 + srow) * K + k0 + scol, &As[wid * 32][0]);
    GLL16(A + (size_t)(m0 + wid * 32 + 16 + srow) * K + k0 + scol,
          &As[wid * 32 + 16][0]);
    GLL16(Bt + (size_t)(n0 + wid * 32 + srow) * K + k0 + scol,
          &Bs[wid * 32][0]);
    GLL16(Bt + (size_t)(n0 + wid * 32 + 16 + srow) * K + k0 + scol,
          &Bs[wid * 32 + 16][0]);
    asm volatile("s_waitcnt vmcnt(0)" ::: "memory");
    __syncthreads();

    f16x8 a[4], b[4];
#pragma unroll
    for (int m = 0; m < 4; ++m)
      a[m] = *(const f16x8*)&As[wr + m * 16 + (lane & 15)][(lane >> 4) * 8];
#pragma unroll
    for (int n = 0; n < 4; ++n)
      b[n] = *(const f16x8*)&Bs[wc + n * 16 + (lane & 15)][(lane >> 4) * 8];
#pragma unroll
    for (int m = 0; m < 4; ++m)
#pragma unroll
      for (int n = 0; n < 4; ++n)
        acc[m][n] = __builtin_amdgcn_mfma_f32_16x16x32_f16(a[m], b[n],
                                                           acc[m][n], 0, 0, 0);
    __syncthreads();
  }

#pragma unroll
  for (int m = 0; m < 4; ++m)
#pragma unroll
    for (int n = 0; n < 4; ++n) {
      const int col = n0 + wc + n * 16 + (lane & 15);
      const float bb = bias[col];
#pragma unroll
      for (int j = 0; j < 4; ++j) {
        const int row = m0 + wr + m * 16 + (lane >> 4) * 4 + j;
        if (OUT16)
          outh[(size_t)row * N + col] = __float2half(acc[m][n][j] + bb);
        else
          outf[(size_t)row * N + col] = acc[m][n][j] + bb;
      }
    }
}

// ---------------------------------------------------------------------------
// MFMA flash attention, fp16 inputs, fp32 softmax/accum, fp16 ctx out.
// Block = 256 (4 waves); wave w owns q rows [qbase+16w, +16); all waves share
// KV tiles of 64 (double-buffered LDS). K staged via global_load_lds with
// inverse-swizzled source; V reg-staged + written transposed (swizzled);
// P routed through per-wave swizzled LDS to form PV's A-fragment.
// ---------------------------------------------------------------------------
__global__ __launch_bounds__(256) void attention_mfma(
    const __half* __restrict__ q, const __half* __restrict__ k,
    const __half* __restrict__ v, __half* __restrict__ ctx) {
  __shared__ _Float16 Kl[2][64][64];   // [k-row][d], swizzled rows
  __shared__ _Float16 Vt[2][64][64];   // [d][k-row], swizzled rows
  __shared__ _Float16 Pl[4][16][64];   // per-wave [q][k], swizzled rows

  const int tid = threadIdx.x;
  const int wid = tid >> 6, lane = tid & 63;
  const int qt = gridDim.x - 1 - blockIdx.x;  // big tiles first
  const int bh = blockIdx.y;
  const int b = bh >> 4, h = bh & 15;
  const int qbase = qt * 64;
  const int g = lane >> 4, r = lane & 15;

  const __half* qhead = q + ((size_t)b * TDIM) * CDIM + h * DDIM;
  const __half* khead = k + ((size_t)b * TDIM) * CDIM + h * DDIM;
  const __half* vhead = v + ((size_t)b * TDIM) * CDIM + h * DDIM;

  // Q fragments (persistent): row = qbase + wid*16 + r, elems g*8 + kk*32
  f16x8 qf[2];
  {
    const __half* qrow = qhead + (size_t)(qbase + wid * 16 + r) * CDIM;
    qf[0] = *(const f16x8*)(qrow + g * 8);
    qf[1] = *(const f16x8*)(qrow + g * 8 + 32);
  }

  // V staging: thread covers V row tid>>2, cols (tid&3)*16 + {0..7, 8..15}
  const int vrow = tid >> 2, vcol = (tid & 3) * 16;
  // K GLL per-lane source offsets (inverse swizzle): call c covers rows c*8..+7
  const int kr8 = lane >> 3;  // row within 8-row group
  const int c0 = wid * 2, c1 = wid * 2 + 1;
  const int kcol0 = (((lane & 7) ^ kr8 ^ c0) & 7) * 8;
  const int kcol1 = (((lane & 7) ^ kr8 ^ c1) & 7) * 8;

  f32x4 acc_c[4] = {};
  float mj[4] = {-3.0e38f, -3.0e38f, -3.0e38f, -3.0e38f};
  float lj[4] = {};

  const int nt = qt + 1;

  // ---- prologue: stage tile 0 ----
  f16x8 va, vb;
  {
    const __half* vsrc = vhead + (size_t)vrow * CDIM + vcol;
    va = *(const f16x8*)(vsrc);
    vb = *(const f16x8*)(vsrc + 8);
    GLL16(khead + (size_t)(c0 * 8 + kr8) * CDIM + kcol0, &Kl[0][c0 * 8][0]);
    GLL16(khead + (size_t)(c1 * 8 + kr8) * CDIM + kcol1, &Kl[0][c1 * 8][0]);
  }
  asm volatile("s_waitcnt vmcnt(0)" ::: "memory");
  __builtin_amdgcn_sched_barrier(0);
  {
    char* vt0 = (char*)&Vt[0][0][0];
#pragma unroll
    for (int i = 0; i < 8; ++i) {
      const int d0 = vcol + i, d1 = vcol + 8 + i;
      *(_Float16*)(vt0 + d0 * 128 + ((vrow * 2) ^ SWZ(d0))) = va[i];
      *(_Float16*)(vt0 + d1 * 128 + ((vrow * 2) ^ SWZ(d1))) = vb[i];
    }
  }
  __syncthreads();

  for (int t = 0; t < nt; ++t) {
    const int cur = t & 1, nxt = cur ^ 1;
    // ---- issue next-tile staging (loads only) ----
    if (t + 1 < nt) {
      const __half* vsrc =
          vhead + (size_t)((t + 1) * 64 + vrow) * CDIM + vcol;
      va = *(const f16x8*)(vsrc);
      vb = *(const f16x8*)(vsrc + 8);
      GLL16(khead + (size_t)((t + 1) * 64 + c0 * 8 + kr8) * CDIM + kcol0,
            &Kl[nxt][c0 * 8][0]);
      GLL16(khead + (size_t)((t + 1) * 64 + c1 * 8 + kr8) * CDIM + kcol1,
            &Kl[nxt][c1 * 8][0]);
    }

    // ---- QK^T: S[16q x 64k] ----
    f32x4 s[4] = {};
    const char* klb = (const char*)&Kl[cur][0][0];
#pragma unroll
    for (int kk = 0; kk < 2; ++kk) {
#pragma unroll
      for (int n = 0; n < 4; ++n) {
        const int kcol = n * 16 + r;
        f16x8 kf = *(const f16x8*)(klb + kcol * 128 +
                                   ((g * 16 + kk * 64) ^ SWZ(kcol)));
        s[n] = __builtin_amdgcn_mfma_f32_16x16x32_f16(qf[kk], kf, s[n], 0, 0, 0);
      }
    }

    // ---- scale + causal mask (only diagonal tile) ----
    if (t == qt) {
#pragma unroll
      for (int n = 0; n < 4; ++n) {
        const int kg = t * 64 + n * 16 + r;
#pragma unroll
        for (int j = 0; j < 4; ++j) {
          const int qg = qbase + wid * 16 + g * 4 + j;
          s[n][j] = (kg <= qg) ? s[n][j] * 0.125f : -3.0e38f;
        }
      }
    } else {
#pragma unroll
      for (int n = 0; n < 4; ++n)
#pragma unroll
        for (int j = 0; j < 4; ++j) s[n][j] *= 0.125f;
    }

    // ---- online softmax (rows spread over lane&15; reduce via shfl_xor) ----
    float pj[4][4];
#pragma unroll
    for (int j = 0; j < 4; ++j) {
      float mx = fmaxf(fmaxf(s[0][j], s[1][j]), fmaxf(s[2][j], s[3][j]));
      mx = fmaxf(mx, __shfl_xor(mx, 1));
      mx = fmaxf(mx, __shfl_xor(mx, 2));
      mx = fmaxf(mx, __shfl_xor(mx, 4));
      mx = fmaxf(mx, __shfl_xor(mx, 8));
      const float mnew = fmaxf(mj[j], mx);
      const float corr = __expf(mj[j] - mnew);
      float sum = 0.f;
#pragma unroll
      for (int n = 0; n < 4; ++n) {
        pj[n][j] = __expf(s[n][j] - mnew);
        sum += pj[n][j];
      }
      sum += __shfl_xor(sum, 1);
      sum += __shfl_xor(sum, 2);
      sum += __shfl_xor(sum, 4);
      sum += __shfl_xor(sum, 8);
      lj[j] = lj[j] * corr + sum;
      mj[j] = mnew;
#pragma unroll
      for (int n = 0; n < 4; ++n) acc_c[n][j] *= corr;
    }

    // ---- P -> per-wave LDS (fp16, swizzled) ----
    char* pb = (char*)&Pl[wid][0][0];
#pragma unroll
    for (int n = 0; n < 4; ++n)
#pragma unroll
      for (int j = 0; j < 4; ++j) {
        const int qw = g * 4 + j, kcol = n * 16 + r;
        *(_Float16*)(pb + qw * 128 + ((kcol * 2) ^ SWZ(qw))) =
            (_Float16)pj[n][j];
      }

    // ---- PV: ctx[16q x 64d] += P @ V ----
    const char* vtb = (const char*)&Vt[cur][0][0];
#pragma unroll
    for (int kk = 0; kk < 2; ++kk) {
      f16x8 pa =
          *(const f16x8*)(pb + r * 128 + ((g * 16 + kk * 64) ^ SWZ(r)));
#pragma unroll
      for (int n = 0; n < 4; ++n) {
        const int d = n * 16 + r;
        f16x8 vf =
            *(const f16x8*)(vtb + d * 128 + ((g * 16 + kk * 64) ^ SWZ(d)));
        acc_c[n] =
            __builtin_amdgcn_mfma_f32_16x16x32_f16(pa, vf, acc_c[n], 0, 0, 0);
      }
    }

    // ---- complete next-tile staging (writes) ----
    if (t + 1 < nt) {
      asm volatile("s_waitcnt vmcnt(0)" ::: "memory");
      __builtin_amdgcn_sched_barrier(0);
      char* vtn = (char*)&Vt[nxt][0][0];
#pragma unroll
      for (int i = 0; i < 8; ++i) {
        const int d0 = vcol + i, d1 = vcol + 8 + i;
        *(_Float16*)(vtn + d0 * 128 + ((vrow * 2) ^ SWZ(d0))) = va[i];
        *(_Float16*)(vtn + d1 * 128 + ((vrow * 2) ^ SWZ(d1))) = vb[i];
      }
    }
    __syncthreads();
  }

  // ---- epilogue: normalize, write fp16 ctx ----
#pragma unroll
  for (int j = 0; j < 4; ++j) {
    const float inv = 1.0f / lj[j];
    const int qg = qbase + wid * 16 + g * 4 + j;
    __half* orow = ctx + ((size_t)(b * TDIM + qg)) * CDIM + h * DDIM;
#pragma unroll
    for (int n = 0; n < 4; ++n)
      orow[n * 16 + r] = __float2half(acc_c[n][j] * inv);
  }
}

// ---------------------------------------------------------------------------
extern "C" void kernel_launch(void* const* d_in, const int* in_sizes, int n_in,
                              void* d_out, int out_size, void* d_ws,
                              size_t ws_size, hipStream_t stream) {
  // 0 hs, 1 mask(unused: implicit causal), 2 Wq, 3 bq, 4 Wk, 5 bk, 6 Wv, 7 bv,
  // 8 Wo, 9 bo, 10..13 routing MLP (dead code)
  const float* hs = (const float*)d_in[0];
  const float* Wq = (const float*)d_in[2];
  const float* bq = (const float*)d_in[3];
  const float* Wk = (const float*)d_in[4];
  const float* bk = (const float*)d_in[5];
  const float* Wv = (const float*)d_in[6];
  const float* bv = (const float*)d_in[7];
  const float* Wo = (const float*)d_in[8];
  const float* bo = (const float*)d_in[9];
  float* out = (float*)d_out;

  const size_t NTOK = (size_t)BDIM * TDIM;  // 4096
  const size_t NELEM = NTOK * CDIM;         // 4M

  // ws: q16,k16,v16 (8MB ea) | hs16 8MB | ctx16 8MB | 4x Wt f16 (2MB ea) = 48MB
  __half* q16 = (__half*)d_ws;
  __half* k16 = q16 + NELEM;
  __half* v16 = k16 + NELEM;
  __half* hs16 = v16 + NELEM;
  __half* ctx16 = hs16 + NELEM;
  __half* wqt = ctx16 + NELEM;
  __half* wkt = wqt + (size_t)CDIM * CDIM;
  __half* wvt = wkt + (size_t)CDIM * CDIM;
  __half* wot = wvt + (size_t)CDIM * CDIM;

  cvt_f16<<<dim3((NELEM / 8 + 255) / 256), dim3(256), 0, stream>>>(
      hs, hs16, (int)(NELEM / 8));
  transpose_cvt<<<dim3(32, 32, 4), dim3(256), 0, stream>>>(
      Wq, Wk, Wv, Wo, wqt, wkt, wvt, wot);

  dim3 gblk(256), ggrid(CDIM / 128, NTOK / 128);  // (8, 32)
  gemm_f16_bt<1><<<ggrid, gblk, 0, stream>>>(hs16, wqt, bq, nullptr, q16,
                                             (int)NTOK, CDIM, CDIM);
  gemm_f16_bt<1><<<ggrid, gblk, 0, stream>>>(hs16, wkt, bk, nullptr, k16,
                                             (int)NTOK, CDIM, CDIM);
  gemm_f16_bt<1><<<ggrid, gblk, 0, stream>>>(hs16, wvt, bv, nullptr, v16,
                                             (int)NTOK, CDIM, CDIM);

  attention_mfma<<<dim3(TDIM / 64, BDIM * HDIM), dim3(256), 0, stream>>>(
      q16, k16, v16, ctx16);

  gemm_f16_bt<0><<<ggrid, gblk, 0, stream>>>(ctx16, wot, bo, out, nullptr,
                                             (int)NTOK, CDIM, CDIM);
}

// Round 6
// 292.887 us; speedup vs baseline: 16.9210x; 1.2517x over previous
//
#include <hip/hip_runtime.h>
#include <hip/hip_fp16.h>
#include <math.h>

// Problem constants
#define BDIM 2
#define TDIM 2048
#define CDIM 1024
#define HDIM 16
#define DDIM 64

typedef _Float16 f16x8 __attribute__((ext_vector_type(8)));
typedef float f32x4 __attribute__((ext_vector_type(4)));

#define GLL16(gsrc, ldst)                                                      \
  __builtin_amdgcn_global_load_lds(                                            \
      (const __attribute__((address_space(1))) unsigned int*)(gsrc),           \
      (__attribute__((address_space(3))) unsigned int*)(ldst), 16, 0, 0)

// XOR swizzle for 128B-stride LDS tiles: spreads 16B slots across banks.
#define SWZ(row) ((((row)&7) ^ (((row) >> 3) & 7)) << 4)

// ---------------------------------------------------------------------------
// fp32 -> fp16 elementwise convert (8 elems/thread)
// ---------------------------------------------------------------------------
__global__ __launch_bounds__(256) void cvt_f16(const float* __restrict__ in,
                                               __half* __restrict__ out,
                                               int n8) {
  int i = blockIdx.x * blockDim.x + threadIdx.x;
  if (i >= n8) return;
  const float4* p = (const float4*)in + (size_t)i * 2;
  float4 a = p[0], b = p[1];
  __half2* o = (__half2*)out + (size_t)i * 4;
  o[0] = __floats2half2_rn(a.x, a.y);
  o[1] = __floats2half2_rn(a.z, a.w);
  o[2] = __floats2half2_rn(b.x, b.y);
  o[3] = __floats2half2_rn(b.z, b.w);
}

// ---------------------------------------------------------------------------
// W [K][N] f32  ->  Wt [N][K] f16   (z selects which of 4 matrices)
// ---------------------------------------------------------------------------
__global__ __launch_bounds__(256) void transpose_cvt(
    const float* __restrict__ w0, const float* __restrict__ w1,
    const float* __restrict__ w2, const float* __restrict__ w3,
    __half* __restrict__ o0, __half* __restrict__ o1, __half* __restrict__ o2,
    __half* __restrict__ o3) {
  const float* src;
  __half* dst;
  switch (blockIdx.z) {
    case 0: src = w0; dst = o0; break;
    case 1: src = w1; dst = o1; break;
    case 2: src = w2; dst = o2; break;
    default: src = w3; dst = o3; break;
  }
  __shared__ float t[32][33];
  const int tx = threadIdx.x & 31, ty = threadIdx.x >> 5;  // 32 x 8
  const int k0 = blockIdx.y * 32, n0 = blockIdx.x * 32;
#pragma unroll
  for (int j = 0; j < 4; ++j)
    t[ty + j * 8][tx] = src[(size_t)(k0 + ty + j * 8) * CDIM + n0 + tx];
  __syncthreads();
#pragma unroll
  for (int j = 0; j < 4; ++j)
    dst[(size_t)(n0 + ty + j * 8) * CDIM + k0 + tx] =
        __float2half(t[tx][ty + j * 8]);
}

// ---------------------------------------------------------------------------
// MFMA GEMM, 2-phase prefetch (T3-min): out = A16[M][K] @ Bt16[N][K]^T + bias.
// NMAT=3 fuses QKV: Bt rows 0..3071 = [WqT;WkT;WvT], outputs land in three
// contiguous [M][1024] matrices at outh + mat*M*1024.
// 128x128 tile, BK=32, 4 waves (2x2 of 64x64), mfma_f32_16x16x32_f16.
// Double-buffered LDS; next tile's global_load_lds issued BEFORE compute;
// __syncthreads (implicit vmcnt drain) completes the prefetch per iter.
// ---------------------------------------------------------------------------
template <int NMAT, int OUT16>
__global__ __launch_bounds__(256) void gemm_f16_bt(
    const __half* __restrict__ A, const __half* __restrict__ Bt,
    const float* __restrict__ bias0, const float* __restrict__ bias1,
    const float* __restrict__ bias2, float* __restrict__ outf,
    __half* __restrict__ outh, int M, int K) {
  __shared__ _Float16 As[2][128][32];
  __shared__ _Float16 Bs[2][128][32];
  const int tid = threadIdx.x;
  const int wid = tid >> 6, lane = tid & 63;
  const int m0 = blockIdx.y * 128, n0 = blockIdx.x * 128;
  const int wr = (wid >> 1) * 64, wc = (wid & 1) * 64;
  const int srow = lane >> 2;
  const int scol = (lane & 3) * 8;

  const __half* asrc = A + (size_t)(m0 + wid * 32 + srow) * K + scol;
  const __half* bsrc = Bt + (size_t)(n0 + wid * 32 + srow) * K + scol;

  f32x4 acc[4][4] = {};
  const int NT = K / 32;

  // prologue: stage tile 0
  GLL16(asrc, &As[0][wid * 32][0]);
  GLL16(asrc + 16 * K, &As[0][wid * 32 + 16][0]);
  GLL16(bsrc, &Bs[0][wid * 32][0]);
  GLL16(bsrc + 16 * K, &Bs[0][wid * 32 + 16][0]);
  __syncthreads();  // barrier lowering drains vmcnt(0)

  for (int t = 0; t < NT; ++t) {
    const int cur = t & 1;
    if (t + 1 < NT) {  // issue next tile's loads (stay in flight over compute)
      const int k0 = (t + 1) * 32;
      GLL16(asrc + k0, &As[cur ^ 1][wid * 32][0]);
      GLL16(asrc + k0 + 16 * K, &As[cur ^ 1][wid * 32 + 16][0]);
      GLL16(bsrc + k0, &Bs[cur ^ 1][wid * 32][0]);
      GLL16(bsrc + k0 + 16 * K, &Bs[cur ^ 1][wid * 32 + 16][0]);
    }
    f16x8 a[4], b[4];
#pragma unroll
    for (int m = 0; m < 4; ++m)
      a[m] =
          *(const f16x8*)&As[cur][wr + m * 16 + (lane & 15)][(lane >> 4) * 8];
#pragma unroll
    for (int n = 0; n < 4; ++n)
      b[n] =
          *(const f16x8*)&Bs[cur][wc + n * 16 + (lane & 15)][(lane >> 4) * 8];
#pragma unroll
    for (int m = 0; m < 4; ++m)
#pragma unroll
      for (int n = 0; n < 4; ++n)
        acc[m][n] = __builtin_amdgcn_mfma_f32_16x16x32_f16(a[m], b[n],
                                                           acc[m][n], 0, 0, 0);
    __syncthreads();  // drains this iter's prefetch + protects As[cur] reuse
  }

  // epilogue
  const float* bias = bias0;
  size_t obase = 0;
  int ncol0 = n0;
  if (NMAT == 3) {
    const int mat = n0 >> 10;
    bias = (mat == 0) ? bias0 : (mat == 1) ? bias1 : bias2;
    obase = (size_t)mat * ((size_t)M * CDIM);
    ncol0 = n0 & 1023;
  }
#pragma unroll
  for (int m = 0; m < 4; ++m)
#pragma unroll
    for (int n = 0; n < 4; ++n) {
      const int col = ncol0 + wc + n * 16 + (lane & 15);
      const float bb = bias[col];
#pragma unroll
      for (int j = 0; j < 4; ++j) {
        const int row = m0 + wr + m * 16 + (lane >> 4) * 4 + j;
        if (OUT16)
          outh[obase + (size_t)row * CDIM + col] =
              __float2half(acc[m][n][j] + bb);
        else
          outf[(size_t)row * CDIM + col] = acc[m][n][j] + bb;
      }
    }
}

// ---------------------------------------------------------------------------
// MFMA flash attention, fp16 inputs, fp32 softmax/accum, fp16 ctx out.
// Block = 256 (4 waves); wave w owns q rows [qbase+16w, +16); all waves share
// KV tiles of 64 (double-buffered LDS). K staged via global_load_lds with
// inverse-swizzled source; V reg-staged + written transposed (swizzled);
// P routed through per-wave swizzled LDS to form PV's A-fragment.
// qt = (bx+by)&31: balances per-CU causal work (x-major dispatch puts ids
// {c,c+256,..} on one CU -> same x; adding y spreads qt by 8 within a CU).
// ---------------------------------------------------------------------------
__global__ __launch_bounds__(256) void attention_mfma(
    const __half* __restrict__ q, const __half* __restrict__ k,
    const __half* __restrict__ v, __half* __restrict__ ctx) {
  __shared__ _Float16 Kl[2][64][64];   // [k-row][d], swizzled rows
  __shared__ _Float16 Vt[2][64][64];   // [d][k-row], swizzled rows
  __shared__ _Float16 Pl[4][16][64];   // per-wave [q][k], swizzled rows

  const int tid = threadIdx.x;
  const int wid = tid >> 6, lane = tid & 63;
  const int qt = (blockIdx.x + blockIdx.y) & 31;  // balanced mapping
  const int bh = blockIdx.y;
  const int b = bh >> 4, h = bh & 15;
  const int qbase = qt * 64;
  const int g = lane >> 4, r = lane & 15;

  const __half* qhead = q + ((size_t)b * TDIM) * CDIM + h * DDIM;
  const __half* khead = k + ((size_t)b * TDIM) * CDIM + h * DDIM;
  const __half* vhead = v + ((size_t)b * TDIM) * CDIM + h * DDIM;

  // Q fragments (persistent): row = qbase + wid*16 + r, elems g*8 + kk*32
  f16x8 qf[2];
  {
    const __half* qrow = qhead + (size_t)(qbase + wid * 16 + r) * CDIM;
    qf[0] = *(const f16x8*)(qrow + g * 8);
    qf[1] = *(const f16x8*)(qrow + g * 8 + 32);
  }

  // V staging: thread covers V row tid>>2, cols (tid&3)*16 + {0..7, 8..15}
  const int vrow = tid >> 2, vcol = (tid & 3) * 16;
  // K GLL per-lane source offsets (inverse swizzle): call c covers rows c*8..+7
  const int kr8 = lane >> 3;  // row within 8-row group
  const int c0 = wid * 2, c1 = wid * 2 + 1;
  const int kcol0 = (((lane & 7) ^ kr8 ^ c0) & 7) * 8;
  const int kcol1 = (((lane & 7) ^ kr8 ^ c1) & 7) * 8;

  f32x4 acc_c[4] = {};
  float mj[4] = {-3.0e38f, -3.0e38f, -3.0e38f, -3.0e38f};
  float lj[4] = {};

  const int nt = qt + 1;

  // ---- prologue: stage tile 0 ----
  f16x8 va, vb;
  {
    const __half* vsrc = vhead + (size_t)vrow * CDIM + vcol;
    va = *(const f16x8*)(vsrc);
    vb = *(const f16x8*)(vsrc + 8);
    GLL16(khead + (size_t)(c0 * 8 + kr8) * CDIM + kcol0, &Kl[0][c0 * 8][0]);
    GLL16(khead + (size_t)(c1 * 8 + kr8) * CDIM + kcol1, &Kl[0][c1 * 8][0]);
  }
  asm volatile("s_waitcnt vmcnt(0)" ::: "memory");
  __builtin_amdgcn_sched_barrier(0);
  {
    char* vt0 = (char*)&Vt[0][0][0];
#pragma unroll
    for (int i = 0; i < 8; ++i) {
      const int d0 = vcol + i, d1 = vcol + 8 + i;
      *(_Float16*)(vt0 + d0 * 128 + ((vrow * 2) ^ SWZ(d0))) = va[i];
      *(_Float16*)(vt0 + d1 * 128 + ((vrow * 2) ^ SWZ(d1))) = vb[i];
    }
  }
  __syncthreads();

  for (int t = 0; t < nt; ++t) {
    const int cur = t & 1, nxt = cur ^ 1;
    // ---- issue next-tile staging (loads only) ----
    if (t + 1 < nt) {
      const __half* vsrc =
          vhead + (size_t)((t + 1) * 64 + vrow) * CDIM + vcol;
      va = *(const f16x8*)(vsrc);
      vb = *(const f16x8*)(vsrc + 8);
      GLL16(khead + (size_t)((t + 1) * 64 + c0 * 8 + kr8) * CDIM + kcol0,
            &Kl[nxt][c0 * 8][0]);
      GLL16(khead + (size_t)((t + 1) * 64 + c1 * 8 + kr8) * CDIM + kcol1,
            &Kl[nxt][c1 * 8][0]);
    }

    // ---- QK^T: S[16q x 64k] ----
    f32x4 s[4] = {};
    const char* klb = (const char*)&Kl[cur][0][0];
#pragma unroll
    for (int kk = 0; kk < 2; ++kk) {
#pragma unroll
      for (int n = 0; n < 4; ++n) {
        const int kcol = n * 16 + r;
        f16x8 kf = *(const f16x8*)(klb + kcol * 128 +
                                   ((g * 16 + kk * 64) ^ SWZ(kcol)));
        s[n] =
            __builtin_amdgcn_mfma_f32_16x16x32_f16(qf[kk], kf, s[n], 0, 0, 0);
      }
    }

    // ---- scale + causal mask (only diagonal tile) ----
    if (t == qt) {
#pragma unroll
      for (int n = 0; n < 4; ++n) {
        const int kg = t * 64 + n * 16 + r;
#pragma unroll
        for (int j = 0; j < 4; ++j) {
          const int qg = qbase + wid * 16 + g * 4 + j;
          s[n][j] = (kg <= qg) ? s[n][j] * 0.125f : -3.0e38f;
        }
      }
    } else {
#pragma unroll
      for (int n = 0; n < 4; ++n)
#pragma unroll
        for (int j = 0; j < 4; ++j) s[n][j] *= 0.125f;
    }

    // ---- online softmax (rows spread over lane&15; reduce via shfl_xor) ----
    float pj[4][4];
#pragma unroll
    for (int j = 0; j < 4; ++j) {
      float mx = fmaxf(fmaxf(s[0][j], s[1][j]), fmaxf(s[2][j], s[3][j]));
      mx = fmaxf(mx, __shfl_xor(mx, 1));
      mx = fmaxf(mx, __shfl_xor(mx, 2));
      mx = fmaxf(mx, __shfl_xor(mx, 4));
      mx = fmaxf(mx, __shfl_xor(mx, 8));
      const float mnew = fmaxf(mj[j], mx);
      const float corr = __expf(mj[j] - mnew);
      float sum = 0.f;
#pragma unroll
      for (int n = 0; n < 4; ++n) {
        pj[n][j] = __expf(s[n][j] - mnew);
        sum += pj[n][j];
      }
      sum += __shfl_xor(sum, 1);
      sum += __shfl_xor(sum, 2);
      sum += __shfl_xor(sum, 4);
      sum += __shfl_xor(sum, 8);
      lj[j] = lj[j] * corr + sum;
      mj[j] = mnew;
#pragma unroll
      for (int n = 0; n < 4; ++n) acc_c[n][j] *= corr;
    }

    // ---- P -> per-wave LDS (fp16, swizzled) ----
    char* pb = (char*)&Pl[wid][0][0];
#pragma unroll
    for (int n = 0; n < 4; ++n)
#pragma unroll
      for (int j = 0; j < 4; ++j) {
        const int qw = g * 4 + j, kcol = n * 16 + r;
        *(_Float16*)(pb + qw * 128 + ((kcol * 2) ^ SWZ(qw))) =
            (_Float16)pj[n][j];
      }

    // ---- PV: ctx[16q x 64d] += P @ V ----
    const char* vtb = (const char*)&Vt[cur][0][0];
#pragma unroll
    for (int kk = 0; kk < 2; ++kk) {
      f16x8 pa =
          *(const f16x8*)(pb + r * 128 + ((g * 16 + kk * 64) ^ SWZ(r)));
#pragma unroll
      for (int n = 0; n < 4; ++n) {
        const int d = n * 16 + r;
        f16x8 vf =
            *(const f16x8*)(vtb + d * 128 + ((g * 16 + kk * 64) ^ SWZ(d)));
        acc_c[n] =
            __builtin_amdgcn_mfma_f32_16x16x32_f16(pa, vf, acc_c[n], 0, 0, 0);
      }
    }

    // ---- complete next-tile staging (writes) ----
    if (t + 1 < nt) {
      asm volatile("s_waitcnt vmcnt(0)" ::: "memory");
      __builtin_amdgcn_sched_barrier(0);
      char* vtn = (char*)&Vt[nxt][0][0];
#pragma unroll
      for (int i = 0; i < 8; ++i) {
        const int d0 = vcol + i, d1 = vcol + 8 + i;
        *(_Float16*)(vtn + d0 * 128 + ((vrow * 2) ^ SWZ(d0))) = va[i];
        *(_Float16*)(vtn + d1 * 128 + ((vrow * 2) ^ SWZ(d1))) = vb[i];
      }
    }
    __syncthreads();
  }

  // ---- epilogue: normalize, write fp16 ctx ----
#pragma unroll
  for (int j = 0; j < 4; ++j) {
    const float inv = 1.0f / lj[j];
    const int qg = qbase + wid * 16 + g * 4 + j;
    __half* orow = ctx + ((size_t)(b * TDIM + qg)) * CDIM + h * DDIM;
#pragma unroll
    for (int n = 0; n < 4; ++n)
      orow[n * 16 + r] = __float2half(acc_c[n][j] * inv);
  }
}

// ---------------------------------------------------------------------------
extern "C" void kernel_launch(void* const* d_in, const int* in_sizes, int n_in,
                              void* d_out, int out_size, void* d_ws,
                              size_t ws_size, hipStream_t stream) {
  // 0 hs, 1 mask(unused: implicit causal), 2 Wq, 3 bq, 4 Wk, 5 bk, 6 Wv, 7 bv,
  // 8 Wo, 9 bo, 10..13 routing MLP (dead code)
  const float* hs = (const float*)d_in[0];
  const float* Wq = (const float*)d_in[2];
  const float* bq = (const float*)d_in[3];
  const float* Wk = (const float*)d_in[4];
  const float* bk = (const float*)d_in[5];
  const float* Wv = (const float*)d_in[6];
  const float* bv = (const float*)d_in[7];
  const float* Wo = (const float*)d_in[8];
  const float* bo = (const float*)d_in[9];
  float* out = (float*)d_out;

  const size_t NTOK = (size_t)BDIM * TDIM;  // 4096
  const size_t NELEM = NTOK * CDIM;         // 4M

  // ws: q16,k16,v16 (8MB ea, contiguous = fused QKV output) | hs16 8MB |
  // ctx16 8MB | WqT,WkT,WvT (contiguous = fused Bt[3072][1024]), WoT = 48MB
  __half* q16 = (__half*)d_ws;
  __half* k16 = q16 + NELEM;
  __half* v16 = k16 + NELEM;
  __half* hs16 = v16 + NELEM;
  __half* ctx16 = hs16 + NELEM;
  __half* wqt = ctx16 + NELEM;
  __half* wkt = wqt + (size_t)CDIM * CDIM;
  __half* wvt = wkt + (size_t)CDIM * CDIM;
  __half* wot = wvt + (size_t)CDIM * CDIM;

  cvt_f16<<<dim3((NELEM / 8 + 255) / 256), dim3(256), 0, stream>>>(
      hs, hs16, (int)(NELEM / 8));
  transpose_cvt<<<dim3(32, 32, 4), dim3(256), 0, stream>>>(
      Wq, Wk, Wv, Wo, wqt, wkt, wvt, wot);

  // fused QKV projection: N=3072, outputs into q16|k16|v16
  dim3 gblk(256);
  gemm_f16_bt<3, 1><<<dim3(24, 32), gblk, 0, stream>>>(
      hs16, wqt, bq, bk, bv, nullptr, q16, (int)NTOK, CDIM);

  attention_mfma<<<dim3(TDIM / 64, BDIM * HDIM), dim3(256), 0, stream>>>(
      q16, k16, v16, ctx16);

  gemm_f16_bt<1, 0><<<dim3(8, 32), gblk, 0, stream>>>(
      ctx16, wot, bo, bo, bo, out, nullptr, (int)NTOK, CDIM);
}

// Round 9
// 258.091 us; speedup vs baseline: 19.2023x; 1.1348x over previous
//
#include <hip/hip_runtime.h>
#include <hip/hip_fp16.h>
#include <math.h>

// Problem constants
#define BDIM 2
#define TDIM 2048
#define CDIM 1024
#define HDIM 16
#define DDIM 64

typedef _Float16 f16x8 __attribute__((ext_vector_type(8)));
typedef _Float16 f16x4 __attribute__((ext_vector_type(4)));
typedef float f32x4 __attribute__((ext_vector_type(4)));

#define GLL16(gsrc, ldst)                                                      \
  __builtin_amdgcn_global_load_lds(                                            \
      (const __attribute__((address_space(1))) unsigned int*)(gsrc),           \
      (__attribute__((address_space(3))) unsigned int*)(ldst), 16, 0, 0)

// XOR swizzle for 128B-stride LDS tiles: spreads 16B slots across banks.
#define SWZ(row) ((((row)&7) ^ (((row) >> 3) & 7)) << 4)

// scale * log2(e): softmax computed in exp2 domain (exactly equivalent)
#define SCALE_LOG2E 0.1803368801111204f

// ---------------------------------------------------------------------------
// fp32 -> fp16 elementwise convert (8 elems/thread)
// ---------------------------------------------------------------------------
__global__ __launch_bounds__(256) void cvt_f16(const float* __restrict__ in,
                                               __half* __restrict__ out,
                                               int n8) {
  int i = blockIdx.x * blockDim.x + threadIdx.x;
  if (i >= n8) return;
  const float4* p = (const float4*)in + (size_t)i * 2;
  float4 a = p[0], b = p[1];
  __half2* o = (__half2*)out + (size_t)i * 4;
  o[0] = __floats2half2_rn(a.x, a.y);
  o[1] = __floats2half2_rn(a.z, a.w);
  o[2] = __floats2half2_rn(b.x, b.y);
  o[3] = __floats2half2_rn(b.z, b.w);
}

// ---------------------------------------------------------------------------
// W [K][N] f32  ->  Wt [N][K] f16   (z selects which of 4 matrices)
// ---------------------------------------------------------------------------
__global__ __launch_bounds__(256) void transpose_cvt(
    const float* __restrict__ w0, const float* __restrict__ w1,
    const float* __restrict__ w2, const float* __restrict__ w3,
    __half* __restrict__ o0, __half* __restrict__ o1, __half* __restrict__ o2,
    __half* __restrict__ o3) {
  const float* src;
  __half* dst;
  switch (blockIdx.z) {
    case 0: src = w0; dst = o0; break;
    case 1: src = w1; dst = o1; break;
    case 2: src = w2; dst = o2; break;
    default: src = w3; dst = o3; break;
  }
  __shared__ float t[32][33];
  const int tx = threadIdx.x & 31, ty = threadIdx.x >> 5;  // 32 x 8
  const int k0 = blockIdx.y * 32, n0 = blockIdx.x * 32;
#pragma unroll
  for (int j = 0; j < 4; ++j)
    t[ty + j * 8][tx] = src[(size_t)(k0 + ty + j * 8) * CDIM + n0 + tx];
  __syncthreads();
#pragma unroll
  for (int j = 0; j < 4; ++j)
    dst[(size_t)(n0 + ty + j * 8) * CDIM + k0 + tx] =
        __float2half(t[tx][ty + j * 8]);
}

// ---------------------------------------------------------------------------
// MFMA GEMM, 2-phase prefetch: out = A16[M][K] @ Bt16[N][K]^T + bias.
// NMAT=3 fuses QKV. 128x128 tile, BK=32, 4 waves, mfma_f32_16x16x32_f16.
// ---------------------------------------------------------------------------
template <int NMAT, int OUT16>
__global__ __launch_bounds__(256) void gemm_f16_bt(
    const __half* __restrict__ A, const __half* __restrict__ Bt,
    const float* __restrict__ bias0, const float* __restrict__ bias1,
    const float* __restrict__ bias2, float* __restrict__ outf,
    __half* __restrict__ outh, int M, int K) {
  __shared__ _Float16 As[2][128][32];
  __shared__ _Float16 Bs[2][128][32];
  const int tid = threadIdx.x;
  const int wid = tid >> 6, lane = tid & 63;
  const int m0 = blockIdx.y * 128, n0 = blockIdx.x * 128;
  const int wr = (wid >> 1) * 64, wc = (wid & 1) * 64;
  const int srow = lane >> 2;
  const int scol = (lane & 3) * 8;

  const __half* asrc = A + (size_t)(m0 + wid * 32 + srow) * K + scol;
  const __half* bsrc = Bt + (size_t)(n0 + wid * 32 + srow) * K + scol;

  f32x4 acc[4][4] = {};
  const int NT = K / 32;

  GLL16(asrc, &As[0][wid * 32][0]);
  GLL16(asrc + 16 * K, &As[0][wid * 32 + 16][0]);
  GLL16(bsrc, &Bs[0][wid * 32][0]);
  GLL16(bsrc + 16 * K, &Bs[0][wid * 32 + 16][0]);
  __syncthreads();  // barrier lowering drains vmcnt(0)

  for (int t = 0; t < NT; ++t) {
    const int cur = t & 1;
    if (t + 1 < NT) {
      const int k0 = (t + 1) * 32;
      GLL16(asrc + k0, &As[cur ^ 1][wid * 32][0]);
      GLL16(asrc + k0 + 16 * K, &As[cur ^ 1][wid * 32 + 16][0]);
      GLL16(bsrc + k0, &Bs[cur ^ 1][wid * 32][0]);
      GLL16(bsrc + k0 + 16 * K, &Bs[cur ^ 1][wid * 32 + 16][0]);
    }
    f16x8 a[4], b[4];
#pragma unroll
    for (int m = 0; m < 4; ++m)
      a[m] =
          *(const f16x8*)&As[cur][wr + m * 16 + (lane & 15)][(lane >> 4) * 8];
#pragma unroll
    for (int n = 0; n < 4; ++n)
      b[n] =
          *(const f16x8*)&Bs[cur][wc + n * 16 + (lane & 15)][(lane >> 4) * 8];
#pragma unroll
    for (int m = 0; m < 4; ++m)
#pragma unroll
      for (int n = 0; n < 4; ++n)
        acc[m][n] = __builtin_amdgcn_mfma_f32_16x16x32_f16(a[m], b[n],
                                                           acc[m][n], 0, 0, 0);
    __syncthreads();
  }

  const float* bias = bias0;
  size_t obase = 0;
  int ncol0 = n0;
  if (NMAT == 3) {
    const int mat = n0 >> 10;
    bias = (mat == 0) ? bias0 : (mat == 1) ? bias1 : bias2;
    obase = (size_t)mat * ((size_t)M * CDIM);
    ncol0 = n0 & 1023;
  }
#pragma unroll
  for (int m = 0; m < 4; ++m)
#pragma unroll
    for (int n = 0; n < 4; ++n) {
      const int col = ncol0 + wc + n * 16 + (lane & 15);
      const float bb = bias[col];
#pragma unroll
      for (int j = 0; j < 4; ++j) {
        const int row = m0 + wr + m * 16 + (lane >> 4) * 4 + j;
        if (OUT16)
          outh[obase + (size_t)row * CDIM + col] =
              __float2half(acc[m][n][j] + bb);
        else
          outf[(size_t)row * CDIM + col] = acc[m][n][j] + bb;
      }
    }
}

// ---------------------------------------------------------------------------
// MFMA flash attention, SWAPPED operands: S^T = mfma(K,Q), ctx^T = mfma(Vt,Pt).
// Each lane owns ONE q-row (q = r = lane&15); its 64 k-scores per tile live in
// 16 registers (4 kb-blocks x 4 j) spread over the 4 lanes with same r
// (g = lane>>4). Row-reduce = in-register + 2 shfl_xor (16,32). m,l are
// per-lane scalars -> rescale applies directly to the transposed accumulator.
// P packed as ds_write_b64 quads. Softmax in exp2 domain (scale*log2e).
// ---------------------------------------------------------------------------
__global__ __launch_bounds__(256) void attention_mfma(
    const __half* __restrict__ q, const __half* __restrict__ k,
    const __half* __restrict__ v, __half* __restrict__ ctx) {
  __shared__ _Float16 Kl[2][64][64];  // [k-row][d], swizzled rows
  __shared__ _Float16 Vt[2][64][64];  // [d][k-row], swizzled rows
  __shared__ _Float16 Pl[4][16][64];  // per-wave [q][k], swizzled rows

  const int tid = threadIdx.x;
  const int wid = tid >> 6, lane = tid & 63;
  const int qt = (blockIdx.x + blockIdx.y) & 31;  // balanced per-CU causal mix
  const int bh = blockIdx.y;
  const int b = bh >> 4, h = bh & 15;
  const int qbase = qt * 64;
  const int g = lane >> 4, r = lane & 15;

  const __half* qhead = q + ((size_t)b * TDIM) * CDIM + h * DDIM;
  const __half* khead = k + ((size_t)b * TDIM) * CDIM + h * DDIM;
  const __half* vhead = v + ((size_t)b * TDIM) * CDIM + h * DDIM;

  // Q fragment (B-operand of S^T): row qbase+wid*16+r, elems g*8 + kk*32
  f16x8 qf[2];
  {
    const __half* qrow = qhead + (size_t)(qbase + wid * 16 + r) * CDIM;
    qf[0] = *(const f16x8*)(qrow + g * 8);
    qf[1] = *(const f16x8*)(qrow + g * 8 + 32);
  }

  // V staging: thread covers V row tid>>2, cols (tid&3)*16 + {0..7, 8..15}
  const int vrow = tid >> 2, vcol = (tid & 3) * 16;
  // K GLL per-lane source offsets (inverse swizzle): call c covers rows c*8..+7
  const int kr8 = lane >> 3;
  const int c0 = wid * 2, c1 = wid * 2 + 1;
  const int kcol0 = (((lane & 7) ^ kr8 ^ c0) & 7) * 8;
  const int kcol1 = (((lane & 7) ^ kr8 ^ c1) & 7) * 8;

  f32x4 accT[4] = {};  // accT[n][j]: d = n*16+g*4+j, q-row = r
  float m = -3.0e38f, l = 0.0f;

  const int nt = qt + 1;

  // ---- prologue: stage tile 0 ----
  f16x8 va, vb;
  {
    const __half* vsrc = vhead + (size_t)vrow * CDIM + vcol;
    va = *(const f16x8*)(vsrc);
    vb = *(const f16x8*)(vsrc + 8);
    GLL16(khead + (size_t)(c0 * 8 + kr8) * CDIM + kcol0, &Kl[0][c0 * 8][0]);
    GLL16(khead + (size_t)(c1 * 8 + kr8) * CDIM + kcol1, &Kl[0][c1 * 8][0]);
  }
  asm volatile("s_waitcnt vmcnt(0)" ::: "memory");
  __builtin_amdgcn_sched_barrier(0);
  {
    char* vt0 = (char*)&Vt[0][0][0];
#pragma unroll
    for (int i = 0; i < 8; ++i) {
      const int d0 = vcol + i, d1 = vcol + 8 + i;
      *(_Float16*)(vt0 + d0 * 128 + ((vrow * 2) ^ SWZ(d0))) = va[i];
      *(_Float16*)(vt0 + d1 * 128 + ((vrow * 2) ^ SWZ(d1))) = vb[i];
    }
  }
  __syncthreads();

  for (int t = 0; t < nt; ++t) {
    const int cur = t & 1, nxt = cur ^ 1;
    // ---- issue next-tile staging (loads only) ----
    if (t + 1 < nt) {
      const __half* vsrc = vhead + (size_t)((t + 1) * 64 + vrow) * CDIM + vcol;
      va = *(const f16x8*)(vsrc);
      vb = *(const f16x8*)(vsrc + 8);
      GLL16(khead + (size_t)((t + 1) * 64 + c0 * 8 + kr8) * CDIM + kcol0,
            &Kl[nxt][c0 * 8][0]);
      GLL16(khead + (size_t)((t + 1) * 64 + c1 * 8 + kr8) * CDIM + kcol1,
            &Kl[nxt][c1 * 8][0]);
    }

    // ---- S^T[64k x 16q] = K @ Q^T ----
    f32x4 sT[4] = {};
    const char* klb = (const char*)&Kl[cur][0][0];
#pragma unroll
    for (int kk = 0; kk < 2; ++kk) {
#pragma unroll
      for (int kb = 0; kb < 4; ++kb) {
        const int krow = kb * 16 + r;
        f16x8 kf = *(const f16x8*)(klb + krow * 128 +
                                   ((g * 16 + kk * 64) ^ SWZ(krow)));
        sT[kb] =
            __builtin_amdgcn_mfma_f32_16x16x32_f16(kf, qf[kk], sT[kb], 0, 0, 0);
      }
    }

    // ---- scale (exp2 domain) + causal mask (diagonal tile only) ----
    const int qg = qbase + wid * 16 + r;
    if (t == qt) {
#pragma unroll
      for (int kb = 0; kb < 4; ++kb) {
        const int kg = t * 64 + kb * 16 + g * 4;
#pragma unroll
        for (int j = 0; j < 4; ++j)
          sT[kb][j] =
              (kg + j <= qg) ? sT[kb][j] * SCALE_LOG2E : -3.0e38f;
      }
    } else {
#pragma unroll
      for (int kb = 0; kb < 4; ++kb)
#pragma unroll
        for (int j = 0; j < 4; ++j) sT[kb][j] *= SCALE_LOG2E;
    }

    // ---- online softmax: per-lane row state, 2+2 shfl over g ----
    float mx = sT[0][0];
#pragma unroll
    for (int kb = 0; kb < 4; ++kb)
#pragma unroll
      for (int j = 0; j < 4; ++j) mx = fmaxf(mx, sT[kb][j]);
    mx = fmaxf(mx, __shfl_xor(mx, 16));
    mx = fmaxf(mx, __shfl_xor(mx, 32));
    const float mnew = fmaxf(m, mx);
    const float corr = exp2f(m - mnew);
    float psum = 0.f;
    float pv[4][4];
#pragma unroll
    for (int kb = 0; kb < 4; ++kb)
#pragma unroll
      for (int j = 0; j < 4; ++j) {
        pv[kb][j] = exp2f(sT[kb][j] - mnew);
        psum += pv[kb][j];
      }
    psum += __shfl_xor(psum, 16);
    psum += __shfl_xor(psum, 32);
    l = l * corr + psum;
    m = mnew;
#pragma unroll
    for (int n = 0; n < 4; ++n) accT[n] *= corr;

    // ---- P^T route: 4x ds_write_b64 quads into per-wave Pl[q=r][k] ----
    char* pb = (char*)&Pl[wid][0][0];
#pragma unroll
    for (int kb = 0; kb < 4; ++kb) {
      f16x4 pq;
#pragma unroll
      for (int j = 0; j < 4; ++j) pq[j] = (_Float16)pv[kb][j];
      *(f16x4*)(pb + r * 128 + ((kb * 32 + g * 8) ^ SWZ(r))) = pq;
    }

    // ---- ctx^T += V^T @ P^T ----
    const char* vtb = (const char*)&Vt[cur][0][0];
#pragma unroll
    for (int kk = 0; kk < 2; ++kk) {
      f16x8 pa =
          *(const f16x8*)(pb + r * 128 + ((g * 16 + kk * 64) ^ SWZ(r)));
#pragma unroll
      for (int n = 0; n < 4; ++n) {
        const int vd = n * 16 + r;
        f16x8 vf =
            *(const f16x8*)(vtb + vd * 128 + ((g * 16 + kk * 64) ^ SWZ(vd)));
        accT[n] =
            __builtin_amdgcn_mfma_f32_16x16x32_f16(vf, pa, accT[n], 0, 0, 0);
      }
    }

    // ---- complete next-tile V staging (writes); barrier drains K GLL ----
    if (t + 1 < nt) {
      asm volatile("s_waitcnt vmcnt(2)" ::: "memory");  // va,vb only
      __builtin_amdgcn_sched_barrier(0);
      char* vtn = (char*)&Vt[nxt][0][0];
#pragma unroll
      for (int i = 0; i < 8; ++i) {
        const int d0 = vcol + i, d1 = vcol + 8 + i;
        *(_Float16*)(vtn + d0 * 128 + ((vrow * 2) ^ SWZ(d0))) = va[i];
        *(_Float16*)(vtn + d1 * 128 + ((vrow * 2) ^ SWZ(d1))) = vb[i];
      }
    }
    __syncthreads();
  }

  // ---- epilogue: normalize, write fp16 ctx (8B quads) ----
  const float inv = 1.0f / l;
  const int qg = qbase + wid * 16 + r;
  __half* orow = ctx + ((size_t)(b * TDIM + qg)) * CDIM + h * DDIM;
#pragma unroll
  for (int n = 0; n < 4; ++n) {
    f16x4 ov;
#pragma unroll
    for (int j = 0; j < 4; ++j) ov[j] = (_Float16)(accT[n][j] * inv);
    *(f16x4*)(orow + n * 16 + g * 4) = ov;
  }
}

// ---------------------------------------------------------------------------
extern "C" void kernel_launch(void* const* d_in, const int* in_sizes, int n_in,
                              void* d_out, int out_size, void* d_ws,
                              size_t ws_size, hipStream_t stream) {
  // 0 hs, 1 mask(unused: implicit causal), 2 Wq, 3 bq, 4 Wk, 5 bk, 6 Wv, 7 bv,
  // 8 Wo, 9 bo, 10..13 routing MLP (dead code)
  const float* hs = (const float*)d_in[0];
  const float* Wq = (const float*)d_in[2];
  const float* bq = (const float*)d_in[3];
  const float* Wk = (const float*)d_in[4];
  const float* bk = (const float*)d_in[5];
  const float* Wv = (const float*)d_in[6];
  const float* bv = (const float*)d_in[7];
  const float* Wo = (const float*)d_in[8];
  const float* bo = (const float*)d_in[9];
  float* out = (float*)d_out;

  const size_t NTOK = (size_t)BDIM * TDIM;  // 4096
  const size_t NELEM = NTOK * CDIM;         // 4M

  __half* q16 = (__half*)d_ws;
  __half* k16 = q16 + NELEM;
  __half* v16 = k16 + NELEM;
  __half* hs16 = v16 + NELEM;
  __half* ctx16 = hs16 + NELEM;
  __half* wqt = ctx16 + NELEM;
  __half* wkt = wqt + (size_t)CDIM * CDIM;
  __half* wvt = wkt + (size_t)CDIM * CDIM;
  __half* wot = wvt + (size_t)CDIM * CDIM;

  cvt_f16<<<dim3((NELEM / 8 + 255) / 256), dim3(256), 0, stream>>>(
      hs, hs16, (int)(NELEM / 8));
  transpose_cvt<<<dim3(32, 32, 4), dim3(256), 0, stream>>>(
      Wq, Wk, Wv, Wo, wqt, wkt, wvt, wot);

  dim3 gblk(256);
  gemm_f16_bt<3, 1><<<dim3(24, 32), gblk, 0, stream>>>(
      hs16, wqt, bq, bk, bv, nullptr, q16, (int)NTOK, CDIM);

  attention_mfma<<<dim3(TDIM / 64, BDIM * HDIM), dim3(256), 0, stream>>>(
      q16, k16, v16, ctx16);

  gemm_f16_bt<1, 0><<<dim3(8, 32), gblk, 0, stream>>>(
      ctx16, wot, bo, bo, bo, out, nullptr, (int)NTOK, CDIM);
}